// Round 1
// baseline (723.218 us; speedup 1.0000x reference)
//
#include <hip/hip_runtime.h>
#include <math.h>

#define Bn 64
#define Dn 3072
#define Kn 512
#define En 64

static constexpr float BETA = 5.0f;

// ---- workspace layout (float offsets) ----
static constexpr size_t XE_OFF    = 0;          // B*K*E  = 2097152
static constexpr size_t S_OFF     = 2097152;    // K*E    = 32768
static constexpr size_t DOT_OFF   = 2129920;    // B*K    = 32768
static constexpr size_t NPROJ_OFF = 2162688;    // K      = 512
static constexpr size_t XP_OFF    = 2163200;    // B*K    = 32768
static constexpr size_t LAT1_OFF  = 2195968;    // B*E    = 4096
static constexpr size_t LAT2_OFF  = 2200064;    // B*E    = 4096
static constexpr size_t XP2_OFF   = 2204160;    // B*K    = 32768
static constexpr size_t XP2T_OFF  = 2236928;    // K*B    = 32768
static constexpr size_t WRECT_OFF = 2269696;    // K*E    = 32768
static constexpr size_t RECON_OFF = 2302464;    // B*D    = 196608
// total = 2499072 floats = ~10.0 MB

__device__ __forceinline__ float waveAllMax(float v) {
#pragma unroll
  for (int o = 32; o; o >>= 1) v = fmaxf(v, __shfl_xor(v, o));
  return v;
}
__device__ __forceinline__ float waveAllSum(float v) {
#pragma unroll
  for (int o = 32; o; o >>= 1) v += __shfl_xor(v, o);
  return v;
}

// ---- zero the recon accumulator ----
__global__ __launch_bounds__(256) void kInit(float* __restrict__ ws) {
  int g = blockIdx.x * 256 + threadIdx.x;
  *(float4*)&ws[RECON_OFF + (size_t)g * 4] = make_float4(0.f, 0.f, 0.f, 0.f);
}

// ---- transpose w_rec (E,K) -> wrecT (K,E) ----
__global__ __launch_bounds__(256) void kTr(const float* __restrict__ wrec, float* __restrict__ ws) {
  int g = blockIdx.x * 256 + threadIdx.x;   // 0..32767
  int k = g >> 6, e = g & 63;
  ws[WRECT_OFF + g] = wrec[(size_t)e * Kn + k];
}

// ---- Pass A: per-k fused {std-stats, proj-correlation, img GEMM, dot, nproj} ----
// grid = 512 (one block per k), 256 threads
__global__ __launch_bounds__(256) void kA(const float* __restrict__ img,
                                          const float* __restrict__ wproj,
                                          const float* __restrict__ w2,
                                          float* __restrict__ ws) {
  const int k = blockIdx.x;
  const int t = threadIdx.x;
  __shared__ __align__(16) float w_lds[32 * 64];    // [dd][e] natural
  __shared__ __align__(16) float img_lds[32 * 68];  // [dd][b] transposed, pad 68
  __shared__ float wp_sh[32];
  __shared__ float s_sh[64];
  __shared__ float proj_sh[64];

  const int bg = t >> 4;   // 0..15 -> b = bg*4+i
  const int eg = t & 15;   // 0..15 -> e = eg*4+j
  const int es = t & 63;   // stats lane (e for stats, b for dot)
  const int ds = t >> 6;   // wave id 0..3 -> d-slice

  float acc[4][4] = {};
  float ssum = 0.f, ssq = 0.f, pacc = 0.f, dacc = 0.f, npacc = 0.f;

  const float* w2k = w2 + (size_t)k * (Dn * En);
  const float* wpk = wproj + (size_t)k * Dn;

  for (int d0 = 0; d0 < Dn; d0 += 32) {
    __syncthreads();
    // stage w2 tile (contiguous 8 KB)
    {
      const float4* src = (const float4*)(w2k + (size_t)d0 * En);
      float4* dst = (float4*)w_lds;
      dst[t] = src[t];
      dst[t + 256] = src[t + 256];
    }
    // stage image tile transposed -> img_lds[d][b]
#pragma unroll
    for (int m = 0; m < 2; ++m) {
      int f = t + 256 * m;    // 0..511
      int b = f >> 3;         // 0..63
      int dq = f & 7;         // 0..7 (float4 along d)
      float4 v = *(const float4*)&img[(size_t)b * Dn + d0 + dq * 4];
      img_lds[(dq * 4 + 0) * 68 + b] = v.x;
      img_lds[(dq * 4 + 1) * 68 + b] = v.y;
      img_lds[(dq * 4 + 2) * 68 + b] = v.z;
      img_lds[(dq * 4 + 3) * 68 + b] = v.w;
    }
    if (t < 32) wp_sh[t] = wpk[d0 + t];
    __syncthreads();

    // main GEMM: acc[b][e] += img[b,d]*w2[k,d,e]
#pragma unroll 4
    for (int dd = 0; dd < 32; ++dd) {
      float4 a = *(const float4*)&img_lds[dd * 68 + bg * 4];
      float4 w = *(const float4*)&w_lds[dd * 64 + eg * 4];
      acc[0][0] = fmaf(a.x, w.x, acc[0][0]);
      acc[0][1] = fmaf(a.x, w.y, acc[0][1]);
      acc[0][2] = fmaf(a.x, w.z, acc[0][2]);
      acc[0][3] = fmaf(a.x, w.w, acc[0][3]);
      acc[1][0] = fmaf(a.y, w.x, acc[1][0]);
      acc[1][1] = fmaf(a.y, w.y, acc[1][1]);
      acc[1][2] = fmaf(a.y, w.z, acc[1][2]);
      acc[1][3] = fmaf(a.y, w.w, acc[1][3]);
      acc[2][0] = fmaf(a.z, w.x, acc[2][0]);
      acc[2][1] = fmaf(a.z, w.y, acc[2][1]);
      acc[2][2] = fmaf(a.z, w.z, acc[2][2]);
      acc[2][3] = fmaf(a.z, w.w, acc[2][3]);
      acc[3][0] = fmaf(a.w, w.x, acc[3][0]);
      acc[3][1] = fmaf(a.w, w.y, acc[3][1]);
      acc[3][2] = fmaf(a.w, w.z, acc[3][2]);
      acc[3][3] = fmaf(a.w, w.w, acc[3][3]);
    }
    // fused stats: ssum/ssq/proj (per e, this wave's d-slice) and dot (per b)
#pragma unroll
    for (int i = 0; i < 8; ++i) {
      int d = ds * 8 + i;
      float w = w_lds[d * 64 + es];
      float wp = wp_sh[d];
      float im = img_lds[d * 68 + es];
      ssum += w;
      ssq = fmaf(w, w, ssq);
      pacc = fmaf(wp, w, pacc);
      dacc = fmaf(wp, im, dacc);
    }
    if (t < 32) { float wp = wp_sh[t]; npacc = fmaf(wp, wp, npacc); }
  }

  // reductions over the 4 wave-slices (reuse w_lds as scratch)
  __syncthreads();
  w_lds[ds * 64 + es]       = ssum;
  w_lds[256 + ds * 64 + es] = ssq;
  w_lds[512 + ds * 64 + es] = pacc;
  w_lds[768 + ds * 64 + es] = dacc;
  __syncthreads();
  if (t < 64) {
    float s0 = w_lds[t] + w_lds[64 + t] + w_lds[128 + t] + w_lds[192 + t];
    float q0 = w_lds[256 + t] + w_lds[320 + t] + w_lds[384 + t] + w_lds[448 + t];
    float p0 = w_lds[512 + t] + w_lds[576 + t] + w_lds[640 + t] + w_lds[704 + t];
    float dv = w_lds[768 + t] + w_lds[832 + t] + w_lds[896 + t] + w_lds[960 + t];
    float var = (q0 - s0 * s0 * (1.0f / Dn)) * (1.0f / (Dn - 1));
    float sv = 1.0f / (0.01f + sqrtf(fmaxf(var, 0.f)));
    ws[S_OFF + (size_t)k * En + t] = sv;
    s_sh[t] = sv;
    proj_sh[t] = p0;
    ws[DOT_OFF + (size_t)t * Kn + k] = dv;
    // nproj (only lanes <32 accumulated)
    float v = (t < 32) ? npacc : 0.f;
    v = waveAllSum(v);
    if (t == 0) ws[NPROJ_OFF + k] = v;
  }
  __syncthreads();

  // xe[b,k,e] = s[k,e]*(imgsum - projsum)
#pragma unroll
  for (int i = 0; i < 4; ++i) {
    int b = bg * 4 + i;
    int e0 = eg * 4;
    float4 o;
    o.x = s_sh[e0 + 0] * (acc[i][0] - proj_sh[e0 + 0]);
    o.y = s_sh[e0 + 1] * (acc[i][1] - proj_sh[e0 + 1]);
    o.z = s_sh[e0 + 2] * (acc[i][2] - proj_sh[e0 + 2]);
    o.w = s_sh[e0 + 3] * (acc[i][3] - proj_sh[e0 + 3]);
    *(float4*)&ws[XE_OFF + ((size_t)b * Kn + k) * En + e0] = o;
  }
}

// ---- mid1: nimg, xh, softmax->xp, lat1 ----  grid = 64 (b)
__global__ __launch_bounds__(256) void kMid1(const float* __restrict__ img,
                                             float* __restrict__ ws) {
  const int b = blockIdx.x;
  const int t = threadIdx.x;
  const int wid = t >> 6, lane = t & 63;
  __shared__ float xp_sh[512];
  __shared__ float red[16];
  __shared__ float scratch[256];

  float acc = 0.f;
  const float4* irow = (const float4*)(img + (size_t)b * Dn);
#pragma unroll
  for (int i = 0; i < 3; ++i) {
    float4 v = irow[t + 256 * i];
    acc = fmaf(v.x, v.x, acc); acc = fmaf(v.y, v.y, acc);
    acc = fmaf(v.z, v.z, acc); acc = fmaf(v.w, v.w, acc);
  }
  acc = waveAllSum(acc);
  if (lane == 0) red[wid] = acc;
  __syncthreads();
  const float nimg = red[0] + red[1] + red[2] + red[3];

  const float c = -(BETA / Dn);
  float d1 = ws[DOT_OFF + (size_t)b * Kn + t];
  float d2 = ws[DOT_OFF + (size_t)b * Kn + t + 256];
  float np1 = ws[NPROJ_OFF + t];
  float np2 = ws[NPROJ_OFF + t + 256];
  float x1 = c * (nimg - 2.f * d1 + np1);
  float x2 = c * (nimg - 2.f * d2 + np2);

  float m = waveAllMax(fmaxf(x1, x2));
  if (lane == 0) red[4 + wid] = m;
  __syncthreads();
  m = fmaxf(fmaxf(red[4], red[5]), fmaxf(red[6], red[7]));
  float e1 = expf(x1 - m), e2 = expf(x2 - m);
  float sv = waveAllSum(e1 + e2);
  if (lane == 0) red[8 + wid] = sv;
  __syncthreads();
  float inv = 1.f / (red[8] + red[9] + red[10] + red[11]);
  float p1 = e1 * inv, p2 = e2 * inv;
  xp_sh[t] = p1; xp_sh[t + 256] = p2;
  ws[XP_OFF + (size_t)b * Kn + t] = p1;
  ws[XP_OFF + (size_t)b * Kn + t + 256] = p2;
  __syncthreads();

  // lat1[e] = sum_k xp[k]*wrecT[k,e]
  const int e = t & 63, q = t >> 6;
  float lacc = 0.f;
  for (int kk = q * 128; kk < q * 128 + 128; ++kk)
    lacc = fmaf(xp_sh[kk], ws[WRECT_OFF + (size_t)kk * En + e], lacc);
  scratch[q * 64 + e] = lacc;
  __syncthreads();
  if (t < 64)
    ws[LAT1_OFF + (size_t)b * En + t] =
        scratch[t] + scratch[64 + t] + scratch[128 + t] + scratch[192 + t];
}

// ---- mid2: lat2, xh2, softmax->xp2 (+transposed copy) ----  grid = 64 (b)
__global__ __launch_bounds__(256) void kMid2(float* __restrict__ ws) {
  const int b = blockIdx.x;
  const int t = threadIdx.x;
  const int wid = t >> 6, lane = t & 63;
  __shared__ float xp_sh[512];
  __shared__ __align__(16) float l1_sh[64];
  __shared__ float scratch[256];
  __shared__ float red[16];

  xp_sh[t] = ws[XP_OFF + (size_t)b * Kn + t];
  xp_sh[t + 256] = ws[XP_OFF + (size_t)b * Kn + t + 256];
  if (t < 64) l1_sh[t] = ws[LAT1_OFF + (size_t)b * En + t];
  __syncthreads();

  // lat2[e] = sum_k xp[k]*xe[b,k,e]
  const int e = t & 63, q = t >> 6;
  const float* xeb = ws + XE_OFF + (size_t)b * Kn * En;
  float lacc = 0.f;
  for (int kk = q * 128; kk < q * 128 + 128; ++kk)
    lacc = fmaf(xp_sh[kk], xeb[(size_t)kk * En + e], lacc);
  scratch[q * 64 + e] = lacc;
  __syncthreads();
  if (t < 64)
    ws[LAT2_OFF + (size_t)b * En + t] =
        scratch[t] + scratch[64 + t] + scratch[128 + t] + scratch[192 + t];

  // xh2 for k = t and k = t+256
  float h1 = 0.f, h2 = 0.f;
#pragma unroll
  for (int i = 0; i < 16; ++i) {
    float4 l = *(const float4*)&l1_sh[i * 4];
    float4 w1 = *(const float4*)&ws[WRECT_OFF + (size_t)t * En + i * 4];
    float4 w2v = *(const float4*)&ws[WRECT_OFF + ((size_t)t + 256) * En + i * 4];
    float a0 = l.x - w1.x, a1 = l.y - w1.y, a2 = l.z - w1.z, a3 = l.w - w1.w;
    h1 = fmaf(a0, a0, h1); h1 = fmaf(a1, a1, h1);
    h1 = fmaf(a2, a2, h1); h1 = fmaf(a3, a3, h1);
    float b0 = l.x - w2v.x, b1 = l.y - w2v.y, b2 = l.z - w2v.z, b3 = l.w - w2v.w;
    h2 = fmaf(b0, b0, h2); h2 = fmaf(b1, b1, h2);
    h2 = fmaf(b2, b2, h2); h2 = fmaf(b3, b3, h2);
  }
  const float c2 = -(BETA / En);
  float x1 = c2 * h1, x2 = c2 * h2;

  float m = waveAllMax(fmaxf(x1, x2));
  if (lane == 0) red[4 + wid] = m;
  __syncthreads();
  m = fmaxf(fmaxf(red[4], red[5]), fmaxf(red[6], red[7]));
  float e1 = expf(x1 - m), e2 = expf(x2 - m);
  float sv = waveAllSum(e1 + e2);
  if (lane == 0) red[8 + wid] = sv;
  __syncthreads();
  float inv = 1.f / (red[8] + red[9] + red[10] + red[11]);
  float p1 = e1 * inv, p2 = e2 * inv;
  ws[XP2_OFF + (size_t)b * Kn + t] = p1;
  ws[XP2_OFF + (size_t)b * Kn + t + 256] = p2;
  ws[XP2T_OFF + (size_t)t * Bn + b] = p1;
  ws[XP2T_OFF + ((size_t)t + 256) * Bn + b] = p2;
}

// ---- Pass B: recon[b,d] += sum_k xp2[b,k]*( sum_e lat2[b,e]*s[k,e]*w2[k,d,e] + wproj[k,d] )
// grid = (48 d-tiles of 64, 8 k-slices of 64), 256 threads
__global__ __launch_bounds__(256) void kB(const float* __restrict__ wproj,
                                          const float* __restrict__ w2,
                                          float* __restrict__ ws) {
  const int d0 = blockIdx.x * 64;
  const int k0 = blockIdx.y * 64;
  const int t = threadIdx.x;
  const int bg = t >> 4;   // 0..15 -> b = bg*4+i
  const int dg = t & 15;   // 0..15 -> d = d0+dg*4+j
  __shared__ float w_lds[64 * 65];    // [dd][e] pad 65 (scaled by s)
  __shared__ float l2_lds[64 * 66];   // [e][b] pad 66
  __shared__ float xp2_sh[64];
  __shared__ float wp_sh[64];

#pragma unroll
  for (int m = 0; m < 16; ++m) {
    int idx = t + 256 * m;
    int bb = idx >> 6, ee = idx & 63;
    l2_lds[ee * 66 + bb] = ws[LAT2_OFF + idx];
  }

  float out[4][4] = {};

  for (int kk = 0; kk < 64; ++kk) {
    const int k = k0 + kk;
    __syncthreads();
    if (t < 64) {
      xp2_sh[t] = ws[XP2T_OFF + (size_t)k * Bn + t];
      wp_sh[t] = wproj[(size_t)k * Dn + d0 + t];
    }
    const float* wk = w2 + (size_t)k * (Dn * En) + (size_t)d0 * En;
#pragma unroll
    for (int m = 0; m < 4; ++m) {
      int f4 = t + 256 * m;       // 0..1023
      int dd = f4 >> 4, eq = f4 & 15;
      float4 wv = *(const float4*)&wk[(size_t)f4 * 4];
      float4 svv = *(const float4*)&ws[S_OFF + (size_t)k * En + eq * 4];
      w_lds[dd * 65 + eq * 4 + 0] = wv.x * svv.x;
      w_lds[dd * 65 + eq * 4 + 1] = wv.y * svv.y;
      w_lds[dd * 65 + eq * 4 + 2] = wv.z * svv.z;
      w_lds[dd * 65 + eq * 4 + 3] = wv.w * svv.w;
    }
    __syncthreads();

    float p[4][4] = {};
#pragma unroll 4
    for (int e = 0; e < 64; ++e) {
      float a0 = l2_lds[e * 66 + bg * 4 + 0];
      float a1 = l2_lds[e * 66 + bg * 4 + 1];
      float a2 = l2_lds[e * 66 + bg * 4 + 2];
      float a3 = l2_lds[e * 66 + bg * 4 + 3];
      float w0 = l2_lds ? w_lds[(dg * 4 + 0) * 65 + e] : 0.f;
      float w1 = w_lds[(dg * 4 + 1) * 65 + e];
      float w2x = w_lds[(dg * 4 + 2) * 65 + e];
      float w3 = w_lds[(dg * 4 + 3) * 65 + e];
      p[0][0] = fmaf(a0, w0, p[0][0]);
      p[0][1] = fmaf(a0, w1, p[0][1]);
      p[0][2] = fmaf(a0, w2x, p[0][2]);
      p[0][3] = fmaf(a0, w3, p[0][3]);
      p[1][0] = fmaf(a1, w0, p[1][0]);
      p[1][1] = fmaf(a1, w1, p[1][1]);
      p[1][2] = fmaf(a1, w2x, p[1][2]);
      p[1][3] = fmaf(a1, w3, p[1][3]);
      p[2][0] = fmaf(a2, w0, p[2][0]);
      p[2][1] = fmaf(a2, w1, p[2][1]);
      p[2][2] = fmaf(a2, w2x, p[2][2]);
      p[2][3] = fmaf(a2, w3, p[2][3]);
      p[3][0] = fmaf(a3, w0, p[3][0]);
      p[3][1] = fmaf(a3, w1, p[3][1]);
      p[3][2] = fmaf(a3, w2x, p[3][2]);
      p[3][3] = fmaf(a3, w3, p[3][3]);
    }
#pragma unroll
    for (int i = 0; i < 4; ++i) {
      float xv = xp2_sh[bg * 4 + i];
#pragma unroll
      for (int j = 0; j < 4; ++j)
        out[i][j] = fmaf(xv, p[i][j] + wp_sh[dg * 4 + j], out[i][j]);
    }
  }

#pragma unroll
  for (int i = 0; i < 4; ++i)
#pragma unroll
    for (int j = 0; j < 4; ++j)
      atomicAdd(&ws[RECON_OFF + (size_t)(bg * 4 + i) * Dn + d0 + dg * 4 + j], out[i][j]);
}

// ---- loss ----  grid = 64 (b)
__global__ __launch_bounds__(256) void kLoss(const float* __restrict__ img,
                                             const float* __restrict__ ws,
                                             float* __restrict__ out) {
  const int b = blockIdx.x, t = threadIdx.x;
  __shared__ float red[4];
  float acc = 0.f;
  const float4* r4 = (const float4*)(ws + RECON_OFF + (size_t)b * Dn);
  const float4* i4 = (const float4*)(img + (size_t)b * Dn);
#pragma unroll
  for (int i = 0; i < 3; ++i) {
    float4 r = r4[t + 256 * i], v = i4[t + 256 * i];
    float dx = r.x - v.x, dy = r.y - v.y, dz = r.z - v.z, dw = r.w - v.w;
    acc = fmaf(dx, dx, acc); acc = fmaf(dy, dy, acc);
    acc = fmaf(dz, dz, acc); acc = fmaf(dw, dw, acc);
  }
  acc = waveAllSum(acc);
  if ((t & 63) == 0) red[t >> 6] = acc;
  __syncthreads();
  if (t == 0) out[b] = (red[0] + red[1] + red[2] + red[3]) * (1.0f / Dn);
}

extern "C" void kernel_launch(void* const* d_in, const int* in_sizes, int n_in,
                              void* d_out, int out_size, void* d_ws, size_t ws_size,
                              hipStream_t stream) {
  const float* img   = (const float*)d_in[0];
  const float* wproj = (const float*)d_in[1];
  const float* w2    = (const float*)d_in[2];
  const float* wrec  = (const float*)d_in[3];
  float* ws  = (float*)d_ws;
  float* out = (float*)d_out;

  hipLaunchKernelGGL(kInit, dim3(192), dim3(256), 0, stream, ws);
  hipLaunchKernelGGL(kTr,   dim3(128), dim3(256), 0, stream, wrec, ws);
  hipLaunchKernelGGL(kA,    dim3(512), dim3(256), 0, stream, img, wproj, w2, ws);
  hipLaunchKernelGGL(kMid1, dim3(64),  dim3(256), 0, stream, img, ws);
  hipLaunchKernelGGL(kMid2, dim3(64),  dim3(256), 0, stream, ws);
  hipLaunchKernelGGL(kB,    dim3(48, 8), dim3(256), 0, stream, wproj, w2, ws);
  hipLaunchKernelGGL(kLoss, dim3(64),  dim3(256), 0, stream, img, ws, out);
}

// Round 2
// 245.009 us; speedup vs baseline: 2.9518x; 2.9518x over previous
//
#include <hip/hip_runtime.h>
#include <math.h>

#define Bn 64
#define Dn 3072
#define Kn 512
#define En 64

static constexpr float BETA = 5.0f;

// ---- workspace layout (float offsets), total 2,466,304 floats = 9.87 MB ----
static constexpr size_t XE_OFF    = 0;        // xe fp32 [B][K][E] (2097152); later reused: zfrag bf16
static constexpr size_t S_OFF     = 2097152;  // s fp32 [K][E] (32768)
static constexpr size_t DOT_OFF   = 2129920;  // dot fp32 [B][K] (32768); later reused: xp2 bf16
static constexpr size_t NPROJ_OFF = 2162688;  // [K] (512)
static constexpr size_t XP_OFF    = 2163200;  // [B][K] (32768)
static constexpr size_t LAT1_OFF  = 2195968;  // [B][E] (4096)
static constexpr size_t LAT2_OFF  = 2200064;  // [B][E] (4096)
static constexpr size_t XP2_OFF   = 2204160;  // [B][K] (32768)
static constexpr size_t WRECT_OFF = 2236928;  // [K][E] (32768)
static constexpr size_t RECON_OFF = 2269696;  // [B][D] (196608); first 98304 reused early as img A-frags bf16

typedef float  f4  __attribute__((ext_vector_type(4)));
typedef __bf16 bf8 __attribute__((ext_vector_type(8)));
typedef int    i4  __attribute__((ext_vector_type(4)));

union AB { i4 i; bf8 b; };

__device__ __forceinline__ unsigned short bf16b(float x) {
  __bf16 h = (__bf16)x;
  union Cv { __bf16 h; unsigned short u; } c;
  c.h = h;
  return c.u;
}

__device__ __forceinline__ float waveAllMax(float v) {
#pragma unroll
  for (int o = 32; o; o >>= 1) v = fmaxf(v, __shfl_xor(v, o));
  return v;
}
__device__ __forceinline__ float waveAllSum(float v) {
#pragma unroll
  for (int o = 32; o; o >>= 1) v += __shfl_xor(v, o);
  return v;
}

// ---- kPrep: img fp32 -> bf16 A-fragments [dstep 96][btile 4][lane 64][slot 8] ----
__global__ __launch_bounds__(256) void kPrep(const float* __restrict__ img,
                                             float* __restrict__ ws) {
  const int t = threadIdx.x, ds = blockIdx.x;
  const int T = t >> 6, l = t & 63;
  const int b = 16 * T + (l & 15);
  const int d0 = 32 * ds + 8 * (l >> 4);
  const float* p = img + (size_t)b * Dn + d0;
  unsigned short u[8];
#pragma unroll
  for (int j = 0; j < 8; ++j) u[j] = bf16b(p[j]);
  i4 v;
  v.x = (int)u[0] | ((int)u[1] << 16);
  v.y = (int)u[2] | ((int)u[3] << 16);
  v.z = (int)u[4] | ((int)u[5] << 16);
  v.w = (int)u[6] | ((int)u[7] << 16);
  ((i4*)(ws + RECON_OFF))[(ds * 4 + T) * 64 + l] = v;
}

// ---- kTr: w_rec (E,K) -> wrecT (K,E) ----
__global__ __launch_bounds__(256) void kTr(const float* __restrict__ wrec, float* __restrict__ ws) {
  int g = blockIdx.x * 256 + threadIdx.x;
  int k = g >> 6, e = g & 63;
  ws[WRECT_OFF + g] = wrec[(size_t)e * Kn + k];
}

// ---- kDot: dot[b,k] = img . wproj_k  and  nproj[k] = |wproj_k|^2 (MFMA) ----
// grid 32 (k-tiles of 16), 256 thr, wave = btile
__global__ __launch_bounds__(256) void kDot(const float* __restrict__ wproj,
                                            float* __restrict__ ws) {
  const int t = threadIdx.x, w = t >> 6, l = t & 63, elane = l & 15, dgrp = l >> 4;
  const int kk = blockIdx.x * 16 + elane;
  const unsigned short* afr16 = (const unsigned short*)(ws + RECON_OFF);
  const i4* afr = (const i4*)afr16;
  const float* wrow = wproj + (size_t)kk * Dn;
  f4 acc = {0.f, 0.f, 0.f, 0.f};
  float np = 0.f;
  float bwA[8], bwB[8];
  i4 avA, avB;
  avA = afr[(0 * 4 + w) * 64 + l];
#pragma unroll
  for (int j = 0; j < 8; ++j) bwA[j] = wrow[8 * dgrp + j];

#define KD_ITER(BWC, BWN, AVC, AVN, N) {                                         \
    const int np1 = (N) + 1;                                                     \
    if (np1 < 96) {                                                              \
      AVN = afr[(np1 * 4 + w) * 64 + l];                                         \
      _Pragma("unroll")                                                          \
      for (int j = 0; j < 8; ++j) BWN[j] = wrow[(size_t)np1 * 32 + 8 * dgrp + j];\
    }                                                                            \
    bf8 bfr;                                                                     \
    _Pragma("unroll")                                                            \
    for (int j = 0; j < 8; ++j) { float v = BWC[j]; np = fmaf(v, v, np); bfr[j] = (__bf16)v; } \
    AB a; a.i = AVC;                                                             \
    acc = __builtin_amdgcn_mfma_f32_16x16x32_bf16(a.b, bfr, acc, 0, 0, 0);       \
  }

  for (int n = 0; n < 96; n += 2) {
    KD_ITER(bwA, bwB, avA, avB, n)
    KD_ITER(bwB, bwA, avB, avA, n + 1)
  }
#undef KD_ITER
#pragma unroll
  for (int r = 0; r < 4; ++r) {
    int b = 16 * w + 4 * dgrp + r;
    ws[DOT_OFF + (size_t)b * Kn + kk] = acc[r];
  }
  np += __shfl_xor(np, 16);
  np += __shfl_xor(np, 32);
  if (w == 0 && dgrp == 0) ws[NPROJ_OFF + kk] = np;
}

// ---- kA: per-k fused {img GEMM (MFMA), std-stats, proj-correlation} -> xe, s ----
// grid 512 (k), 256 thr; wave = e-tile; B (w2) direct strided loads; A via LDS dbuf
__global__ __launch_bounds__(256) void kA(const float* __restrict__ wproj,
                                          const float* __restrict__ w2,
                                          float* __restrict__ ws) {
  const int k = blockIdx.x, t = threadIdx.x;
  const int w = t >> 6, l = t & 63, elane = l & 15, dgrp = l >> 4;
  const int ecol = 16 * w + elane;
  __shared__ float wp[Dn];
  __shared__ i4 bufA0[256], bufA1[256];
  const float* wpk = wproj + (size_t)k * Dn;
#pragma unroll
  for (int i = 0; i < 3; ++i) ((f4*)wp)[t + 256 * i] = ((const f4*)wpk)[t + 256 * i];
  const i4* afr = (const i4*)(ws + RECON_OFF);
  const float* w2k = w2 + (size_t)k * (Dn * En);
  f4 acc0 = {0.f,0.f,0.f,0.f}, acc1 = {0.f,0.f,0.f,0.f};
  f4 acc2 = {0.f,0.f,0.f,0.f}, acc3 = {0.f,0.f,0.f,0.f};
  float ssum = 0.f, ssq = 0.f, pacc = 0.f;
  float bwA[8], bwB[8];
  i4 avP = afr[(0 * 4 + w) * 64 + l];
#pragma unroll
  for (int j = 0; j < 8; ++j) bwA[j] = w2k[(size_t)(8 * dgrp + j) * 64 + ecol];
  bufA0[w * 64 + l] = avP;
  __syncthreads();

#define KA_ITER(BWC, BWN, BUFC, BUFN, N) {                                       \
    const int np1 = (N) + 1; i4 avn;                                             \
    if (np1 < 96) {                                                              \
      avn = afr[(np1 * 4 + w) * 64 + l];                                         \
      _Pragma("unroll")                                                          \
      for (int j = 0; j < 8; ++j)                                                \
        BWN[j] = w2k[(size_t)(np1 * 32 + 8 * dgrp + j) * 64 + ecol];             \
    }                                                                            \
    bf8 bfr;                                                                     \
    _Pragma("unroll")                                                            \
    for (int j = 0; j < 8; ++j) {                                                \
      float v = BWC[j];                                                          \
      ssum += v; ssq = fmaf(v, v, ssq);                                          \
      pacc = fmaf(wp[(N) * 32 + 8 * dgrp + j], v, pacc);                         \
      bfr[j] = (__bf16)v;                                                        \
    }                                                                            \
    AB a0, a1, a2, a3;                                                           \
    a0.i = BUFC[0 * 64 + l]; a1.i = BUFC[1 * 64 + l];                            \
    a2.i = BUFC[2 * 64 + l]; a3.i = BUFC[3 * 64 + l];                            \
    acc0 = __builtin_amdgcn_mfma_f32_16x16x32_bf16(a0.b, bfr, acc0, 0, 0, 0);    \
    acc1 = __builtin_amdgcn_mfma_f32_16x16x32_bf16(a1.b, bfr, acc1, 0, 0, 0);    \
    acc2 = __builtin_amdgcn_mfma_f32_16x16x32_bf16(a2.b, bfr, acc2, 0, 0, 0);    \
    acc3 = __builtin_amdgcn_mfma_f32_16x16x32_bf16(a3.b, bfr, acc3, 0, 0, 0);    \
    if (np1 < 96) BUFN[w * 64 + l] = avn;                                        \
    __syncthreads();                                                             \
  }

  for (int n = 0; n < 96; n += 2) {
    KA_ITER(bwA, bwB, bufA0, bufA1, n)
    KA_ITER(bwB, bwA, bufA1, bufA0, n + 1)
  }
#undef KA_ITER

  ssum += __shfl_xor(ssum, 16); ssum += __shfl_xor(ssum, 32);
  ssq  += __shfl_xor(ssq, 16);  ssq  += __shfl_xor(ssq, 32);
  pacc += __shfl_xor(pacc, 16); pacc += __shfl_xor(pacc, 32);
  float var = (ssq - ssum * ssum * (1.0f / Dn)) * (1.0f / (Dn - 1));
  float sv = 1.0f / (0.01f + sqrtf(fmaxf(var, 0.f)));
  if (dgrp == 0) ws[S_OFF + (size_t)k * En + ecol] = sv;
#pragma unroll
  for (int T = 0; T < 4; ++T) {
    f4 a = (T == 0) ? acc0 : (T == 1) ? acc1 : (T == 2) ? acc2 : acc3;
#pragma unroll
    for (int r = 0; r < 4; ++r) {
      int b = 16 * T + 4 * dgrp + r;
      ws[XE_OFF + ((size_t)b * Kn + k) * En + ecol] = sv * (a[r] - pacc);
    }
  }
}

// ---- kMid1: nimg, xh, softmax->xp, lat1 ----  grid 64 (b)
__global__ __launch_bounds__(256) void kMid1(const float* __restrict__ img,
                                             float* __restrict__ ws) {
  const int b = blockIdx.x;
  const int t = threadIdx.x;
  const int wid = t >> 6, lane = t & 63;
  __shared__ float xp_sh[512];
  __shared__ float red[16];
  __shared__ float scratch[256];

  float acc = 0.f;
  const f4* irow = (const f4*)(img + (size_t)b * Dn);
#pragma unroll
  for (int i = 0; i < 3; ++i) {
    f4 v = irow[t + 256 * i];
    acc = fmaf(v.x, v.x, acc); acc = fmaf(v.y, v.y, acc);
    acc = fmaf(v.z, v.z, acc); acc = fmaf(v.w, v.w, acc);
  }
  acc = waveAllSum(acc);
  if (lane == 0) red[wid] = acc;
  __syncthreads();
  const float nimg = red[0] + red[1] + red[2] + red[3];

  const float c = -(BETA / Dn);
  float d1 = ws[DOT_OFF + (size_t)b * Kn + t];
  float d2 = ws[DOT_OFF + (size_t)b * Kn + t + 256];
  float np1 = ws[NPROJ_OFF + t];
  float np2 = ws[NPROJ_OFF + t + 256];
  float x1 = c * (nimg - 2.f * d1 + np1);
  float x2 = c * (nimg - 2.f * d2 + np2);

  float m = waveAllMax(fmaxf(x1, x2));
  if (lane == 0) red[4 + wid] = m;
  __syncthreads();
  m = fmaxf(fmaxf(red[4], red[5]), fmaxf(red[6], red[7]));
  float e1 = expf(x1 - m), e2 = expf(x2 - m);
  float sv = waveAllSum(e1 + e2);
  if (lane == 0) red[8 + wid] = sv;
  __syncthreads();
  float inv = 1.f / (red[8] + red[9] + red[10] + red[11]);
  float p1 = e1 * inv, p2 = e2 * inv;
  xp_sh[t] = p1; xp_sh[t + 256] = p2;
  ws[XP_OFF + (size_t)b * Kn + t] = p1;
  ws[XP_OFF + (size_t)b * Kn + t + 256] = p2;
  __syncthreads();

  const int e = t & 63, q = t >> 6;
  float lacc = 0.f;
  for (int kk = q * 128; kk < q * 128 + 128; ++kk)
    lacc = fmaf(xp_sh[kk], ws[WRECT_OFF + (size_t)kk * En + e], lacc);
  scratch[q * 64 + e] = lacc;
  __syncthreads();
  if (t < 64)
    ws[LAT1_OFF + (size_t)b * En + t] =
        scratch[t] + scratch[64 + t] + scratch[128 + t] + scratch[192 + t];
}

// ---- kMid2: lat2, xh2, softmax->xp2 (fp32 + bf16 copy) ----  grid 64 (b)
__global__ __launch_bounds__(256) void kMid2(float* __restrict__ ws) {
  const int b = blockIdx.x;
  const int t = threadIdx.x;
  const int wid = t >> 6, lane = t & 63;
  __shared__ float xp_sh[512];
  __shared__ __align__(16) float l1_sh[64];
  __shared__ float scratch[256];
  __shared__ float red[16];

  xp_sh[t] = ws[XP_OFF + (size_t)b * Kn + t];
  xp_sh[t + 256] = ws[XP_OFF + (size_t)b * Kn + t + 256];
  if (t < 64) l1_sh[t] = ws[LAT1_OFF + (size_t)b * En + t];
  __syncthreads();

  const int e = t & 63, q = t >> 6;
  const float* xeb = ws + XE_OFF + (size_t)b * Kn * En;
  float lacc = 0.f;
  for (int kk = q * 128; kk < q * 128 + 128; ++kk)
    lacc = fmaf(xp_sh[kk], xeb[(size_t)kk * En + e], lacc);
  scratch[q * 64 + e] = lacc;
  __syncthreads();
  if (t < 64)
    ws[LAT2_OFF + (size_t)b * En + t] =
        scratch[t] + scratch[64 + t] + scratch[128 + t] + scratch[192 + t];

  float h1 = 0.f, h2 = 0.f;
#pragma unroll
  for (int i = 0; i < 16; ++i) {
    f4 lv = *(const f4*)&l1_sh[i * 4];
    f4 w1 = *(const f4*)&ws[WRECT_OFF + (size_t)t * En + i * 4];
    f4 w2v = *(const f4*)&ws[WRECT_OFF + ((size_t)t + 256) * En + i * 4];
    float a0 = lv.x - w1.x, a1 = lv.y - w1.y, a2 = lv.z - w1.z, a3 = lv.w - w1.w;
    h1 = fmaf(a0, a0, h1); h1 = fmaf(a1, a1, h1);
    h1 = fmaf(a2, a2, h1); h1 = fmaf(a3, a3, h1);
    float b0 = lv.x - w2v.x, b1 = lv.y - w2v.y, b2 = lv.z - w2v.z, b3 = lv.w - w2v.w;
    h2 = fmaf(b0, b0, h2); h2 = fmaf(b1, b1, h2);
    h2 = fmaf(b2, b2, h2); h2 = fmaf(b3, b3, h2);
  }
  const float c2 = -(BETA / En);
  float x1 = c2 * h1, x2 = c2 * h2;

  float m = waveAllMax(fmaxf(x1, x2));
  if (lane == 0) red[4 + wid] = m;
  __syncthreads();
  m = fmaxf(fmaxf(red[4], red[5]), fmaxf(red[6], red[7]));
  float e1 = expf(x1 - m), e2 = expf(x2 - m);
  float sv = waveAllSum(e1 + e2);
  if (lane == 0) red[8 + wid] = sv;
  __syncthreads();
  float inv = 1.f / (red[8] + red[9] + red[10] + red[11]);
  float p1 = e1 * inv, p2 = e2 * inv;
  ws[XP2_OFF + (size_t)b * Kn + t] = p1;
  ws[XP2_OFF + (size_t)b * Kn + t + 256] = p2;
  unsigned short* xpb = (unsigned short*)(ws + DOT_OFF);
  xpb[(size_t)b * Kn + t] = bf16b(p1);
  xpb[(size_t)b * Kn + t + 256] = bf16b(p2);
}

// ---- kZ: z[b,k,e] = xp2*lat2*s -> bf16 fragment order [S 1024][T 4][lane 64][slot 8] ----
__global__ __launch_bounds__(256) void kZ(float* __restrict__ ws) {
  const int g = blockIdx.x * 256 + threadIdx.x;  // 0..262143
  const int S = g >> 8;
  const int T = (g >> 6) & 3;
  const int l = g & 63;
  const int dgrp = l >> 4;
  const int b = 16 * T + (l & 15);
  const int kd0 = S * 32 + 8 * dgrp;
  const int k = kd0 >> 6;
  const int e0 = kd0 & 63;
  const float xp2v = ws[XP2_OFF + (size_t)b * Kn + k];
  unsigned short u[8];
#pragma unroll
  for (int j = 0; j < 8; ++j) {
    float v = xp2v * ws[LAT2_OFF + (size_t)b * En + e0 + j] * ws[S_OFF + (size_t)k * En + e0 + j];
    u[j] = bf16b(v);
  }
  i4 v;
  v.x = (int)u[0] | ((int)u[1] << 16);
  v.y = (int)u[2] | ((int)u[3] << 16);
  v.z = (int)u[4] | ((int)u[5] << 16);
  v.w = (int)u[6] | ((int)u[7] << 16);
  ((i4*)(ws + XE_OFF))[g] = v;
}

// ---- kRecon: recon[b,d] = sum_k xp2[b,k]*wproj[k,d] (MFMA, initializes RECON) ----
// grid 48 (d-tiles of 64), wave = d-subtile
__global__ __launch_bounds__(256) void kRecon(const float* __restrict__ wproj,
                                              float* __restrict__ ws) {
  const int blk = blockIdx.x, t = threadIdx.x;
  const int w = t >> 6, l = t & 63, elane = l & 15, dgrp = l >> 4;
  const int dA = blk * 64 + 16 * w + elane;
  const unsigned short* xpb = (const unsigned short*)(ws + DOT_OFF);
  f4 acc0 = {0.f,0.f,0.f,0.f}, acc1 = {0.f,0.f,0.f,0.f};
  f4 acc2 = {0.f,0.f,0.f,0.f}, acc3 = {0.f,0.f,0.f,0.f};
  for (int n = 0; n < 16; ++n) {
    bf8 afr;
#pragma unroll
    for (int j = 0; j < 8; ++j)
      afr[j] = (__bf16)wproj[(size_t)(32 * n + 8 * dgrp + j) * Dn + dA];
    AB b0, b1, b2, b3;
    b0.i = *(const i4*)&xpb[(size_t)(0 * 16 + elane) * Kn + 32 * n + 8 * dgrp];
    b1.i = *(const i4*)&xpb[(size_t)(1 * 16 + elane) * Kn + 32 * n + 8 * dgrp];
    b2.i = *(const i4*)&xpb[(size_t)(2 * 16 + elane) * Kn + 32 * n + 8 * dgrp];
    b3.i = *(const i4*)&xpb[(size_t)(3 * 16 + elane) * Kn + 32 * n + 8 * dgrp];
    acc0 = __builtin_amdgcn_mfma_f32_16x16x32_bf16(afr, b0.b, acc0, 0, 0, 0);
    acc1 = __builtin_amdgcn_mfma_f32_16x16x32_bf16(afr, b1.b, acc1, 0, 0, 0);
    acc2 = __builtin_amdgcn_mfma_f32_16x16x32_bf16(afr, b2.b, acc2, 0, 0, 0);
    acc3 = __builtin_amdgcn_mfma_f32_16x16x32_bf16(afr, b3.b, acc3, 0, 0, 0);
  }
#pragma unroll
  for (int T = 0; T < 4; ++T) {
    f4 a = (T == 0) ? acc0 : (T == 1) ? acc1 : (T == 2) ? acc2 : acc3;
#pragma unroll
    for (int r = 0; r < 4; ++r) {
      int bb = 16 * T + elane;
      int dd = blk * 64 + 16 * w + 4 * dgrp + r;
      ws[RECON_OFF + (size_t)bb * Dn + dd] = a[r];
    }
  }
}

// ---- kB: xd2 accumulation: recon[b,d] += sum_kdim z[b,kdim]*w2[kdim,d] ----
// grid (48 d-tiles, 16 k-slices), wave = d-subtile; B (w2) contiguous loads; A (z) via LDS dbuf
__global__ __launch_bounds__(256) void kB(const float* __restrict__ w2,
                                          float* __restrict__ ws) {
  const int dtile = blockIdx.x, ks = blockIdx.y, t = threadIdx.x;
  const int w = t >> 6, l = t & 63, elane = l & 15, dgrp = l >> 4;
  const int d = dtile * 64 + 16 * w + elane;
  __shared__ i4 bufZ0[256], bufZ1[256];
  const i4* zfr = (const i4*)(ws + XE_OFF);
  f4 acc0 = {0.f,0.f,0.f,0.f}, acc1 = {0.f,0.f,0.f,0.f};
  f4 acc2 = {0.f,0.f,0.f,0.f}, acc3 = {0.f,0.f,0.f,0.f};
  float bwA[8], bwB[8];
  i4 avP = zfr[((ks * 64 + 0) * 4 + w) * 64 + l];
  {
    const int kk = ks * 32;
    const float* p = w2 + ((size_t)kk * Dn + d) * En + 8 * dgrp;
#pragma unroll
    for (int j = 0; j < 8; ++j) bwA[j] = p[j];
  }
  bufZ0[w * 64 + l] = avP;
  __syncthreads();

#define KB_ITER(BWC, BWN, BUFC, BUFN, N) {                                       \
    const int np1 = (N) + 1; i4 avn;                                             \
    if (np1 < 64) {                                                              \
      avn = zfr[((ks * 64 + np1) * 4 + w) * 64 + l];                             \
      const int kk = ks * 32 + (np1 >> 1);                                       \
      const int e0 = (np1 & 1) * 32;                                             \
      const float* p = w2 + ((size_t)kk * Dn + d) * En + e0 + 8 * dgrp;          \
      _Pragma("unroll")                                                          \
      for (int j = 0; j < 8; ++j) BWN[j] = p[j];                                 \
    }                                                                            \
    bf8 bfr;                                                                     \
    _Pragma("unroll")                                                            \
    for (int j = 0; j < 8; ++j) bfr[j] = (__bf16)BWC[j];                         \
    AB a0, a1, a2, a3;                                                           \
    a0.i = BUFC[0 * 64 + l]; a1.i = BUFC[1 * 64 + l];                            \
    a2.i = BUFC[2 * 64 + l]; a3.i = BUFC[3 * 64 + l];                            \
    acc0 = __builtin_amdgcn_mfma_f32_16x16x32_bf16(a0.b, bfr, acc0, 0, 0, 0);    \
    acc1 = __builtin_amdgcn_mfma_f32_16x16x32_bf16(a1.b, bfr, acc1, 0, 0, 0);    \
    acc2 = __builtin_amdgcn_mfma_f32_16x16x32_bf16(a2.b, bfr, acc2, 0, 0, 0);    \
    acc3 = __builtin_amdgcn_mfma_f32_16x16x32_bf16(a3.b, bfr, acc3, 0, 0, 0);    \
    if (np1 < 64) BUFN[w * 64 + l] = avn;                                        \
    __syncthreads();                                                             \
  }

  for (int n = 0; n < 64; n += 2) {
    KB_ITER(bwA, bwB, bufZ0, bufZ1, n)
    KB_ITER(bwB, bwA, bufZ1, bufZ0, n + 1)
  }
#undef KB_ITER

#pragma unroll
  for (int T = 0; T < 4; ++T) {
    f4 a = (T == 0) ? acc0 : (T == 1) ? acc1 : (T == 2) ? acc2 : acc3;
#pragma unroll
    for (int r = 0; r < 4; ++r) {
      int b = 16 * T + 4 * dgrp + r;
      atomicAdd(&ws[RECON_OFF + (size_t)b * Dn + d], a[r]);
    }
  }
}

// ---- kLoss ----  grid 64 (b)
__global__ __launch_bounds__(256) void kLoss(const float* __restrict__ img,
                                             const float* __restrict__ ws,
                                             float* __restrict__ out) {
  const int b = blockIdx.x, t = threadIdx.x;
  __shared__ float red[4];
  float acc = 0.f;
  const f4* r4 = (const f4*)(ws + RECON_OFF + (size_t)b * Dn);
  const f4* i4p = (const f4*)(img + (size_t)b * Dn);
#pragma unroll
  for (int i = 0; i < 3; ++i) {
    f4 r = r4[t + 256 * i], v = i4p[t + 256 * i];
    float dx = r.x - v.x, dy = r.y - v.y, dz = r.z - v.z, dw = r.w - v.w;
    acc = fmaf(dx, dx, acc); acc = fmaf(dy, dy, acc);
    acc = fmaf(dz, dz, acc); acc = fmaf(dw, dw, acc);
  }
  acc = waveAllSum(acc);
  if ((t & 63) == 0) red[t >> 6] = acc;
  __syncthreads();
  if (t == 0) out[b] = (red[0] + red[1] + red[2] + red[3]) * (1.0f / Dn);
}

extern "C" void kernel_launch(void* const* d_in, const int* in_sizes, int n_in,
                              void* d_out, int out_size, void* d_ws, size_t ws_size,
                              hipStream_t stream) {
  const float* img   = (const float*)d_in[0];
  const float* wproj = (const float*)d_in[1];
  const float* w2    = (const float*)d_in[2];
  const float* wrec  = (const float*)d_in[3];
  float* ws  = (float*)d_ws;
  float* out = (float*)d_out;

  hipLaunchKernelGGL(kPrep,  dim3(96),  dim3(256), 0, stream, img, ws);
  hipLaunchKernelGGL(kTr,    dim3(128), dim3(256), 0, stream, wrec, ws);
  hipLaunchKernelGGL(kDot,   dim3(32),  dim3(256), 0, stream, wproj, ws);
  hipLaunchKernelGGL(kA,     dim3(512), dim3(256), 0, stream, wproj, w2, ws);
  hipLaunchKernelGGL(kMid1,  dim3(64),  dim3(256), 0, stream, img, ws);
  hipLaunchKernelGGL(kMid2,  dim3(64),  dim3(256), 0, stream, ws);
  hipLaunchKernelGGL(kZ,     dim3(1024),dim3(256), 0, stream, ws);
  hipLaunchKernelGGL(kRecon, dim3(48),  dim3(256), 0, stream, wproj, ws);
  hipLaunchKernelGGL(kB,     dim3(48, 16), dim3(256), 0, stream, w2, ws);
  hipLaunchKernelGGL(kLoss,  dim3(64),  dim3(256), 0, stream, img, ws, out);
}